// Round 1
// baseline (6035.110 us; speedup 1.0000x reference)
//
#include <hip/hip_runtime.h>
#include <hip/hip_bf16.h>

// ---------------------------------------------------------------------------
// Shapes: B=64, P=196, ENC=2048, E=H=A=512, V=10000, L=21 -> T=20
// ---------------------------------------------------------------------------

#define TB 256

// ------------------------- generic fp32 GEMM body --------------------------
// C[m,n] = sum_k A[m,k]*W[k,n] + bias[n] + add0[m,n] + add1[m,n]
// BM=BN=64, BK=32, 256 threads, 4x4 micro-tile per thread.
__device__ __forceinline__ void gemm_body(
    float (*As)[68], float (*Ws)[68],
    const float* __restrict__ A, int lda,
    const float* __restrict__ W, int ldw,
    const float* __restrict__ bias,
    const float* __restrict__ add0, int ld0,
    const float* __restrict__ add1, int ld1,
    float* __restrict__ C, int ldc,
    int nTile, int mTile, int N, int K)
{
    const int tid = threadIdx.x;
    const int tn = tid & 15;
    const int tm = tid >> 4;
    const int n0 = nTile * 64;
    const int m0 = mTile * 64;
    const bool fullN = (n0 + 64 <= N);

    float acc[4][4] = {{0.f}};

    for (int k0 = 0; k0 < K; k0 += 32) {
        // A tile: 64 rows x 32 k (store transposed As[k][m])
        {
            int r  = tid >> 3;          // 0..31
            int cc = (tid & 7) * 4;     // 0..28
            #pragma unroll
            for (int rr = 0; rr < 64; rr += 32) {
                const float4 a = *(const float4*)&A[(size_t)(m0 + rr + r) * lda + (k0 + cc)];
                As[cc + 0][rr + r] = a.x;
                As[cc + 1][rr + r] = a.y;
                As[cc + 2][rr + r] = a.z;
                As[cc + 3][rr + r] = a.w;
            }
        }
        // W tile: 32 k x 64 n
        {
            int r  = tid >> 4;          // 0..15
            int cc = (tid & 15) * 4;    // 0..60
            #pragma unroll
            for (int rr = 0; rr < 32; rr += 16) {
                float4 w;
                if (fullN) {
                    w = *(const float4*)&W[(size_t)(k0 + rr + r) * ldw + (n0 + cc)];
                } else {
                    const float* wr = &W[(size_t)(k0 + rr + r) * ldw];
                    w.x = (n0 + cc + 0 < N) ? wr[n0 + cc + 0] : 0.f;
                    w.y = (n0 + cc + 1 < N) ? wr[n0 + cc + 1] : 0.f;
                    w.z = (n0 + cc + 2 < N) ? wr[n0 + cc + 2] : 0.f;
                    w.w = (n0 + cc + 3 < N) ? wr[n0 + cc + 3] : 0.f;
                }
                *(float4*)&Ws[rr + r][cc] = w;
            }
        }
        __syncthreads();
        #pragma unroll
        for (int kk = 0; kk < 32; ++kk) {
            const float4 a = *(const float4*)&As[kk][tm * 4];
            const float4 w = *(const float4*)&Ws[kk][tn * 4];
            const float av[4] = {a.x, a.y, a.z, a.w};
            const float wv[4] = {w.x, w.y, w.z, w.w};
            #pragma unroll
            for (int i = 0; i < 4; ++i)
                #pragma unroll
                for (int j = 0; j < 4; ++j)
                    acc[i][j] = fmaf(av[i], wv[j], acc[i][j]);
        }
        __syncthreads();
    }

    #pragma unroll
    for (int i = 0; i < 4; ++i) {
        const int m = m0 + tm * 4 + i;
        #pragma unroll
        for (int j = 0; j < 4; ++j) {
            const int n = n0 + tn * 4 + j;
            if (n < N) {
                float v = acc[i][j];
                if (bias) v += bias[n];
                if (add0) v += add0[(size_t)m * ld0 + n];
                if (add1) v += add1[(size_t)m * ld1 + n];
                C[(size_t)m * ldc + n] = v;
            }
        }
    }
}

__global__ __launch_bounds__(TB) void gemm_k(
    const float* __restrict__ A, int lda,
    const float* __restrict__ W, int ldw,
    const float* __restrict__ bias,
    const float* __restrict__ add0, int ld0,
    const float* __restrict__ add1, int ld1,
    float* __restrict__ C, int ldc, int N, int K)
{
    __shared__ float As[32][68];
    __shared__ float Ws[32][68];
    gemm_body(As, Ws, A, lda, W, ldw, bias, add0, ld0, add1, ld1,
              C, ldc, blockIdx.x, blockIdx.y, N, K);
}

// Fused per-step h-GEMM: att2 = h@W_dec_att+b ; gpre = h@W_fbeta+b ; gh = h@W_hh+b_hh
// grid.x = 8 + 32 + 32 = 72 tiles
__global__ __launch_bounds__(TB) void step_hgemm(
    const float* __restrict__ h,
    const float* __restrict__ Wd, const float* __restrict__ bd, float* __restrict__ att2,
    const float* __restrict__ Wf, const float* __restrict__ bf, float* __restrict__ gpre,
    const float* __restrict__ Wh, const float* __restrict__ bh, float* __restrict__ gh)
{
    __shared__ float As[32][68];
    __shared__ float Ws[32][68];
    const int bx = blockIdx.x;
    if (bx < 8) {
        gemm_body(As, Ws, h, 512, Wd, 512,  bd, nullptr, 0, nullptr, 0, att2, 512,  bx,      0, 512,  512);
    } else if (bx < 40) {
        gemm_body(As, Ws, h, 512, Wf, 2048, bf, nullptr, 0, nullptr, 0, gpre, 2048, bx - 8,  0, 2048, 512);
    } else {
        gemm_body(As, Ws, h, 512, Wh, 2048, bh, nullptr, 0, nullptr, 0, gh,   2048, bx - 40, 0, 2048, 512);
    }
}

// ------------------------- attention scores + softmax ----------------------
// one block per b. scores[p] = relu(att1[b,p,:] + att2[b,:]) . W_full ; alpha = softmax_p
__global__ __launch_bounds__(TB) void attn_softmax(
    const float* __restrict__ att1,   // (64,196,512)
    const float* __restrict__ att2,   // (64,512)
    const float* __restrict__ Wfull,  // (512,1)
    float* __restrict__ alpha)        // (64,196)
{
    const int b = blockIdx.x;
    const int tid = threadIdx.x;
    const int wave = tid >> 6;
    const int lane = tid & 63;

    __shared__ float a2[512];
    __shared__ float wf[512];
    __shared__ float sc[196];
    __shared__ float redm[4];
    __shared__ float reds[4];

    for (int i = tid; i < 512; i += TB) {
        a2[i] = att2[b * 512 + i];
        wf[i] = Wfull[i];
    }
    __syncthreads();

    for (int p = wave; p < 196; p += 4) {
        const float* row = att1 + ((size_t)b * 196 + p) * 512;
        float s = 0.f;
        #pragma unroll
        for (int k = lane; k < 512; k += 64) {
            float v = row[k] + a2[k];
            s = fmaf(fmaxf(v, 0.f), wf[k], s);
        }
        #pragma unroll
        for (int o = 32; o; o >>= 1) s += __shfl_xor(s, o);
        if (lane == 0) sc[p] = s;
    }
    __syncthreads();

    float v = (tid < 196) ? sc[tid] : -1e30f;
    float m = v;
    #pragma unroll
    for (int o = 32; o; o >>= 1) m = fmaxf(m, __shfl_xor(m, o));
    if (lane == 0) redm[wave] = m;
    __syncthreads();
    m = fmaxf(fmaxf(redm[0], redm[1]), fmaxf(redm[2], redm[3]));

    float e = (tid < 196) ? expf(v - m) : 0.f;
    float s = e;
    #pragma unroll
    for (int o = 32; o; o >>= 1) s += __shfl_xor(s, o);
    if (lane == 0) reds[wave] = s;
    __syncthreads();
    s = reds[0] + reds[1] + reds[2] + reds[3];

    if (tid < 196) alpha[b * 196 + tid] = e / s;
}

// ------------------------- awe = alpha . features ; gate ; gated_awe -------
// grid (8, 64) : blockIdx.x = e-chunk of 256, blockIdx.y = b
__global__ __launch_bounds__(TB) void awe_gate(
    const float* __restrict__ alpha,     // (64,196)
    const float* __restrict__ features,  // (64,196,2048)
    const float* __restrict__ gpre,      // (64,2048) pre-sigmoid gate
    float* __restrict__ gated)           // (64,2048)
{
    const int b = blockIdx.y;
    const int e = blockIdx.x * TB + threadIdx.x;

    __shared__ float al[196];
    if (threadIdx.x < 196) al[threadIdx.x] = alpha[b * 196 + threadIdx.x];
    __syncthreads();

    const float* f = features + (size_t)b * 196 * 2048 + e;
    float acc = 0.f;
    #pragma unroll 4
    for (int p = 0; p < 196; ++p) acc = fmaf(al[p], f[(size_t)p * 2048], acc);

    const float gp = gpre[b * 2048 + e];
    const float gate = 1.f / (1.f + expf(-gp));
    gated[b * 2048 + e] = gate * acc;
}

// ------------------------- LSTM pointwise ----------------------------------
__global__ __launch_bounds__(TB) void lstm_pw(
    const float* __restrict__ gates,  // (64,2048)
    float* __restrict__ h,            // (64,512)  in: unused, out: h_new
    float* __restrict__ c)            // (64,512)  in: c,     out: c_new
{
    const int idx = blockIdx.x * TB + threadIdx.x;   // 0..32767
    const int b = idx >> 9;
    const int j = idx & 511;
    const float* g = gates + b * 2048;
    const float gi = g[j];
    const float gf = g[j + 512];
    const float gg = g[j + 1024];
    const float go = g[j + 1536];
    const float si = 1.f / (1.f + expf(-gi));
    const float sf = 1.f / (1.f + expf(-gf));
    const float so = 1.f / (1.f + expf(-go));
    const float cn = sf * c[idx] + si * tanhf(gg);
    c[idx] = cn;
    h[idx] = so * tanhf(cn);
}

// ------------------------- precompute helpers ------------------------------
__global__ __launch_bounds__(TB) void mean_feat(
    const float* __restrict__ features, float* __restrict__ mean_enc)
{
    const int b = blockIdx.y;
    const int e = blockIdx.x * TB + threadIdx.x;
    const float* f = features + (size_t)b * 196 * 2048 + e;
    float s = 0.f;
    #pragma unroll 4
    for (int p = 0; p < 196; ++p) s += f[(size_t)p * 2048];
    mean_enc[b * 2048 + e] = s * (1.f / 196.f);
}

__global__ __launch_bounds__(TB) void gather_emb(
    const int* __restrict__ captions,   // (64,21)
    const float* __restrict__ emb,      // (10000,512)
    float* __restrict__ embs)           // (64,20,512)
{
    const int bt = blockIdx.x;          // 0..1279
    const int b = bt / 20;
    const int t = bt % 20;
    const int tok = captions[b * 21 + t];
    for (int e = threadIdx.x; e < 512; e += TB)
        embs[(size_t)bt * 512 + e] = emb[(size_t)tok * 512 + e];
}

// ---------------------------------------------------------------------------
extern "C" void kernel_launch(void* const* d_in, const int* in_sizes, int n_in,
                              void* d_out, int out_size, void* d_ws, size_t ws_size,
                              hipStream_t stream)
{
    const float* features  = (const float*)d_in[0];
    const int*   captions  = (const int*)  d_in[1];
    const float* W_enc_att = (const float*)d_in[2];
    const float* b_enc_att = (const float*)d_in[3];
    const float* W_dec_att = (const float*)d_in[4];
    const float* b_dec_att = (const float*)d_in[5];
    const float* W_full    = (const float*)d_in[6];
    // d_in[7] = b_full : added uniformly to all scores -> softmax invariant, unused
    const float* emb       = (const float*)d_in[8];
    const float* W_ih      = (const float*)d_in[9];
    const float* W_hh      = (const float*)d_in[10];
    const float* b_ih      = (const float*)d_in[11];
    const float* b_hh      = (const float*)d_in[12];
    const float* W_init_h  = (const float*)d_in[13];
    const float* b_init_h  = (const float*)d_in[14];
    const float* W_init_c  = (const float*)d_in[15];
    const float* b_init_c  = (const float*)d_in[16];
    const float* W_fbeta   = (const float*)d_in[17];
    const float* b_fbeta   = (const float*)d_in[18];
    const float* W_fc      = (const float*)d_in[19];
    const float* b_fc      = (const float*)d_in[20];
    float* out = (float*)d_out;

    float* ws = (float*)d_ws;
    size_t off = 0;
    auto alloc = [&](size_t n) { float* p = ws + off; off += n; return p; };

    float* att1  = alloc((size_t)12544 * 512);  // 25.7 MB
    float* eW    = alloc((size_t)64 * 20 * 2048);
    float* embs  = alloc((size_t)64 * 20 * 512);
    float* mean  = alloc(64 * 2048);
    float* h     = alloc(64 * 512);
    float* c     = alloc(64 * 512);
    float* att2  = alloc(64 * 512);
    float* gpre  = alloc(64 * 2048);
    float* gh    = alloc(64 * 2048);
    float* alpha = alloc(64 * 196);
    float* gawe  = alloc(64 * 2048);
    float* gates = alloc(64 * 2048);

    // ---- precompute (step-invariant) ----
    mean_feat<<<dim3(8, 64), TB, 0, stream>>>(features, mean);
    gather_emb<<<1280, TB, 0, stream>>>(captions, emb, embs);
    // h0 / c0
    gemm_k<<<dim3(8, 1), TB, 0, stream>>>(mean, 2048, W_init_h, 512, b_init_h,
                                          nullptr, 0, nullptr, 0, h, 512, 512, 2048);
    gemm_k<<<dim3(8, 1), TB, 0, stream>>>(mean, 2048, W_init_c, 512, b_init_c,
                                          nullptr, 0, nullptr, 0, c, 512, 512, 2048);
    // att1 = features @ W_enc_att + b   (12544 x 512, K=2048)
    gemm_k<<<dim3(8, 196), TB, 0, stream>>>(features, 2048, W_enc_att, 512, b_enc_att,
                                            nullptr, 0, nullptr, 0, att1, 512, 512, 2048);
    // eW[b,t,:] = embs @ W_ih[:512,:] + b_ih   (1280 x 2048, K=512)
    gemm_k<<<dim3(32, 20), TB, 0, stream>>>(embs, 512, W_ih, 2048, b_ih,
                                            nullptr, 0, nullptr, 0, eW, 2048, 2048, 512);

    // ---- sequential decode ----
    for (int t = 0; t < 20; ++t) {
        step_hgemm<<<72, TB, 0, stream>>>(h,
                                          W_dec_att, b_dec_att, att2,
                                          W_fbeta,   b_fbeta,   gpre,
                                          W_hh,      b_hh,      gh);
        attn_softmax<<<64, TB, 0, stream>>>(att1, att2, W_full, alpha);
        awe_gate<<<dim3(8, 64), TB, 0, stream>>>(alpha, features, gpre, gawe);
        // gates = gated_awe @ W_ih[512:,:] + eW[:,t,:] + gh
        gemm_k<<<dim3(32, 1), TB, 0, stream>>>(gawe, 2048, W_ih + (size_t)512 * 2048, 2048,
                                               nullptr, eW + (size_t)t * 2048, 20 * 2048,
                                               gh, 2048, gates, 2048, 2048, 2048);
        lstm_pw<<<128, TB, 0, stream>>>(gates, h, c);
        // preds = h_new @ W_fc + b_fc -> out[:, t, :]
        gemm_k<<<dim3(157, 1), TB, 0, stream>>>(h, 512, W_fc, 10000, b_fc,
                                                nullptr, 0, nullptr, 0,
                                                out + (size_t)t * 10000, 20 * 10000,
                                                10000, 512);
    }
}

// Round 2
// 2060.119 us; speedup vs baseline: 2.9295x; 2.9295x over previous
//
#include <hip/hip_runtime.h>
#include <hip/hip_bf16.h>

// ---------------------------------------------------------------------------
// Shapes: B=64, P=196, ENC=2048, E=H=A=512, V=10000, L=21 -> T=20
// Structure:
//   pre:  mean_feat, gather_emb, h0/c0 (split-K + reduce), att1 (128-tile),
//         eW = embs @ W_ih[:512] + b_ih   (hoisted out of the loop)
//   step: hgemm_part (split-K=4, partials) -> scores -> awe_gate(softmax inline)
//         -> gates_part (split-K=8, partials) -> lstm_pw (reduces partials)
//   post: preds = hseq @ W_fc + b_fc  (one batched GEMM, 1280 x 10000)
// All consumer kernels sum the split-K partials; biases added exactly once.
// ---------------------------------------------------------------------------

#define TB 256

// ------------------------- generic fp32 GEMM body (64x64, 4x4) -------------
__device__ __forceinline__ void gemm_body(
    float (*As)[68], float (*Ws)[68],
    const float* __restrict__ A, int lda,
    const float* __restrict__ W, int ldw,
    float* __restrict__ C, int ldc,
    int nTile, int N, int K)
{
    const int tid = threadIdx.x;
    const int tn = tid & 15;
    const int tm = tid >> 4;
    const int n0 = nTile * 64;
    const bool fullN = (n0 + 64 <= N);

    float acc[4][4] = {{0.f}};

    for (int k0 = 0; k0 < K; k0 += 32) {
        {   // A tile: 64 rows x 32 k (store transposed As[k][m]) ; M == 64
            int r  = tid >> 3;          // 0..31
            int cc = (tid & 7) * 4;     // 0..28
            #pragma unroll
            for (int rr = 0; rr < 64; rr += 32) {
                const float4 a = *(const float4*)&A[(size_t)(rr + r) * lda + (k0 + cc)];
                As[cc + 0][rr + r] = a.x;
                As[cc + 1][rr + r] = a.y;
                As[cc + 2][rr + r] = a.z;
                As[cc + 3][rr + r] = a.w;
            }
        }
        {   // W tile: 32 k x 64 n
            int r  = tid >> 4;          // 0..15
            int cc = (tid & 15) * 4;    // 0..60
            #pragma unroll
            for (int rr = 0; rr < 32; rr += 16) {
                float4 w;
                if (fullN) {
                    w = *(const float4*)&W[(size_t)(k0 + rr + r) * ldw + (n0 + cc)];
                } else {
                    const float* wr = &W[(size_t)(k0 + rr + r) * ldw];
                    w.x = (n0 + cc + 0 < N) ? wr[n0 + cc + 0] : 0.f;
                    w.y = (n0 + cc + 1 < N) ? wr[n0 + cc + 1] : 0.f;
                    w.z = (n0 + cc + 2 < N) ? wr[n0 + cc + 2] : 0.f;
                    w.w = (n0 + cc + 3 < N) ? wr[n0 + cc + 3] : 0.f;
                }
                *(float4*)&Ws[rr + r][cc] = w;
            }
        }
        __syncthreads();
        #pragma unroll
        for (int kk = 0; kk < 32; ++kk) {
            const float4 a = *(const float4*)&As[kk][tm * 4];
            const float4 w = *(const float4*)&Ws[kk][tn * 4];
            const float av[4] = {a.x, a.y, a.z, a.w};
            const float wv[4] = {w.x, w.y, w.z, w.w};
            #pragma unroll
            for (int i = 0; i < 4; ++i)
                #pragma unroll
                for (int j = 0; j < 4; ++j)
                    acc[i][j] = fmaf(av[i], wv[j], acc[i][j]);
        }
        __syncthreads();
    }

    #pragma unroll
    for (int i = 0; i < 4; ++i) {
        const int m = tm * 4 + i;
        #pragma unroll
        for (int j = 0; j < 4; ++j) {
            const int n = n0 + tn * 4 + j;
            if (n < N) C[(size_t)m * ldc + n] = acc[i][j];
        }
    }
}

// Pure split-K partial GEMM: Cpart[ks][64][N(ldc)] = A[:, ksK:(ks+1)K] @ W[ksK:...]
__global__ __launch_bounds__(TB) void gemm_part(
    const float* __restrict__ A, int lda,
    const float* __restrict__ W, int ldw,
    float* __restrict__ Cpart, int ldc, int N, int Kchunk)
{
    __shared__ float As[32][68];
    __shared__ float Ws[32][68];
    const int ks = blockIdx.y;
    gemm_body(As, Ws,
              A + (size_t)ks * Kchunk, lda,
              W + (size_t)ks * Kchunk * ldw, ldw,
              Cpart + (size_t)ks * 64 * ldc, ldc,
              blockIdx.x, N, Kchunk);
}

// Fused per-step h-GEMM partials: hga_part[ks][64][4608]
// cols 0..511 att2 (W_dec_att), 512..2559 gpre (W_fbeta), 2560..4607 gh (W_hh)
// grid (72, 4), Kchunk = 128
__global__ __launch_bounds__(TB) void step_hgemm_part(
    const float* __restrict__ h,
    const float* __restrict__ Wd,
    const float* __restrict__ Wf,
    const float* __restrict__ Wh,
    float* __restrict__ hga_part)
{
    __shared__ float As[32][68];
    __shared__ float Ws[32][68];
    const int bx = blockIdx.x;
    const int ks = blockIdx.y;
    const float* W; int ldw, ntile, nbase, N;
    if (bx < 8)       { W = Wd; ldw = 512;  ntile = bx;      nbase = 0;    N = 512;  }
    else if (bx < 40) { W = Wf; ldw = 2048; ntile = bx - 8;  nbase = 512;  N = 2048; }
    else              { W = Wh; ldw = 2048; ntile = bx - 40; nbase = 2560; N = 2048; }
    gemm_body(As, Ws,
              h + ks * 128, 512,
              W + (size_t)ks * 128 * ldw, ldw,
              hga_part + (size_t)ks * 64 * 4608 + nbase, 4608,
              ntile, N, 128);
}

// ------------------------- 128x64-tile GEMM (8x4 micro) --------------------
// C[m,n] = A[m,:] @ W[:,n] + bias[n].  M must be a multiple of 128.
// XCD-bijective block swizzle for L2 locality on the A re-reads.
__global__ __launch_bounds__(TB) void gemm128_k(
    const float* __restrict__ A, int lda,
    const float* __restrict__ W, int ldw,
    const float* __restrict__ bias,
    float* __restrict__ C, int ldc, int N, int K)
{
    __shared__ float As[32][132];
    __shared__ float Ws[32][68];

    // bijective XCD swizzle (m204): consecutive work chunks land on one XCD
    const int tot = gridDim.x * gridDim.y;
    const int lin = blockIdx.x + gridDim.x * blockIdx.y;
    const int xcd = lin & 7;
    const int j   = lin >> 3;
    const int q = tot >> 3, r = tot & 7;
    const int base = (xcd < r) ? xcd * (q + 1) : r * (q + 1) + (xcd - r) * q;
    const int lin2 = base + j;
    const int bx = lin2 % gridDim.x;
    const int by = lin2 / gridDim.x;

    const int tid = threadIdx.x;
    const int tn = tid & 15;
    const int tm = tid >> 4;
    const int n0 = bx * 64;
    const int m0 = by * 128;
    const bool fullN = (n0 + 64 <= N);

    float acc[8][4] = {{0.f}};

    for (int k0 = 0; k0 < K; k0 += 32) {
        {   // A: 128 rows x 32 k -> transposed As[k][m]
            int rr0 = tid >> 3;         // 0..31
            int cc  = (tid & 7) * 4;    // 0..28
            #pragma unroll
            for (int rr = 0; rr < 128; rr += 32) {
                const float4 a = *(const float4*)&A[(size_t)(m0 + rr + rr0) * lda + (k0 + cc)];
                As[cc + 0][rr + rr0] = a.x;
                As[cc + 1][rr + rr0] = a.y;
                As[cc + 2][rr + rr0] = a.z;
                As[cc + 3][rr + rr0] = a.w;
            }
        }
        {   // W: 32 k x 64 n
            int rr0 = tid >> 4;
            int cc  = (tid & 15) * 4;
            #pragma unroll
            for (int rr = 0; rr < 32; rr += 16) {
                float4 w;
                if (fullN) {
                    w = *(const float4*)&W[(size_t)(k0 + rr + rr0) * ldw + (n0 + cc)];
                } else {
                    const float* wr = &W[(size_t)(k0 + rr + rr0) * ldw];
                    w.x = (n0 + cc + 0 < N) ? wr[n0 + cc + 0] : 0.f;
                    w.y = (n0 + cc + 1 < N) ? wr[n0 + cc + 1] : 0.f;
                    w.z = (n0 + cc + 2 < N) ? wr[n0 + cc + 2] : 0.f;
                    w.w = (n0 + cc + 3 < N) ? wr[n0 + cc + 3] : 0.f;
                }
                *(float4*)&Ws[rr + rr0][cc] = w;
            }
        }
        __syncthreads();
        #pragma unroll
        for (int kk = 0; kk < 32; ++kk) {
            const float4 a0 = *(const float4*)&As[kk][tm * 8];
            const float4 a1 = *(const float4*)&As[kk][tm * 8 + 4];
            const float4 w  = *(const float4*)&Ws[kk][tn * 4];
            const float av[8] = {a0.x, a0.y, a0.z, a0.w, a1.x, a1.y, a1.z, a1.w};
            const float wv[4] = {w.x, w.y, w.z, w.w};
            #pragma unroll
            for (int i = 0; i < 8; ++i)
                #pragma unroll
                for (int jj = 0; jj < 4; ++jj)
                    acc[i][jj] = fmaf(av[i], wv[jj], acc[i][jj]);
        }
        __syncthreads();
    }

    #pragma unroll
    for (int i = 0; i < 8; ++i) {
        const int m = m0 + tm * 8 + i;
        if (fullN) {
            const int n = n0 + tn * 4;
            float4 o;
            o.x = acc[i][0] + (bias ? bias[n + 0] : 0.f);
            o.y = acc[i][1] + (bias ? bias[n + 1] : 0.f);
            o.z = acc[i][2] + (bias ? bias[n + 2] : 0.f);
            o.w = acc[i][3] + (bias ? bias[n + 3] : 0.f);
            *(float4*)&C[(size_t)m * ldc + n] = o;
        } else {
            #pragma unroll
            for (int jj = 0; jj < 4; ++jj) {
                const int n = n0 + tn * 4 + jj;
                if (n < N) C[(size_t)m * ldc + n] = acc[i][jj] + (bias ? bias[n] : 0.f);
            }
        }
    }
}

// ------------------------- attention scores --------------------------------
// grid (64, 49): b = bx, each of 4 waves handles p = by*4 + wave
__global__ __launch_bounds__(TB) void scores_k(
    const float* __restrict__ att1,      // (64,196,512)
    const float* __restrict__ hga_part,  // (4,64,4608), att2 = cols 0..511
    const float* __restrict__ bd,        // (512,)
    const float* __restrict__ Wfull,     // (512,)
    float* __restrict__ scores)          // (64,196)
{
    const int b = blockIdx.x;
    const int tid = threadIdx.x;
    const int wave = tid >> 6;
    const int lane = tid & 63;

    __shared__ float a2[512];
    __shared__ float wf[512];

    for (int i = tid; i < 512; i += TB) {
        float v = bd[i];
        #pragma unroll
        for (int s = 0; s < 4; ++s)
            v += hga_part[(size_t)s * 64 * 4608 + (size_t)b * 4608 + i];
        a2[i] = v;
        wf[i] = Wfull[i];
    }
    __syncthreads();

    const int p = blockIdx.y * 4 + wave;
    const float* row = att1 + ((size_t)b * 196 + p) * 512;
    float s = 0.f;
    #pragma unroll
    for (int k = lane; k < 512; k += 64) {
        float v = row[k] + a2[k];
        s = fmaf(fmaxf(v, 0.f), wf[k], s);
    }
    #pragma unroll
    for (int o = 32; o; o >>= 1) s += __shfl_xor(s, o);
    if (lane == 0) scores[b * 196 + p] = s;
}

// ---------------- softmax (inline) + awe + gate -----------------------------
// grid (8, 64): blockIdx.x = e-chunk of 256, blockIdx.y = b
__global__ __launch_bounds__(TB) void awe_gate(
    const float* __restrict__ scores,    // (64,196)
    const float* __restrict__ features,  // (64,196,2048)
    const float* __restrict__ hga_part,  // (4,64,4608), gpre = cols 512..2559
    const float* __restrict__ bf,        // (2048,)
    float* __restrict__ gated)           // (64,2048)
{
    const int b = blockIdx.y;
    const int tid = threadIdx.x;
    const int wave = tid >> 6;
    const int lane = tid & 63;
    const int eg = blockIdx.x * TB + tid;

    __shared__ float al[196];
    __shared__ float redm[4];
    __shared__ float reds[4];

    float sv = (tid < 196) ? scores[b * 196 + tid] : -1e30f;
    float m = sv;
    #pragma unroll
    for (int o = 32; o; o >>= 1) m = fmaxf(m, __shfl_xor(m, o));
    if (lane == 0) redm[wave] = m;
    __syncthreads();
    m = fmaxf(fmaxf(redm[0], redm[1]), fmaxf(redm[2], redm[3]));

    float e = (tid < 196) ? expf(sv - m) : 0.f;
    float s = e;
    #pragma unroll
    for (int o = 32; o; o >>= 1) s += __shfl_xor(s, o);
    if (lane == 0) reds[wave] = s;
    __syncthreads();
    s = reds[0] + reds[1] + reds[2] + reds[3];

    if (tid < 196) al[tid] = e / s;
    __syncthreads();

    const float* f = features + (size_t)b * 196 * 2048 + eg;
    float acc = 0.f;
    #pragma unroll 4
    for (int p = 0; p < 196; ++p) acc = fmaf(al[p], f[(size_t)p * 2048], acc);

    float gp = bf[eg];
    #pragma unroll
    for (int ss = 0; ss < 4; ++ss)
        gp += hga_part[(size_t)ss * 64 * 4608 + (size_t)b * 4608 + 512 + eg];
    const float gate = 1.f / (1.f + expf(-gp));
    gated[b * 2048 + eg] = gate * acc;
}

// ------------------------- LSTM pointwise (reduces all partials) -----------
__global__ __launch_bounds__(TB) void lstm_pw(
    const float* __restrict__ gates_part,  // (8,64,2048)
    const float* __restrict__ hga_part,    // (4,64,4608), gh = cols 2560..4607
    const float* __restrict__ eW,          // (64,20,2048), includes b_ih
    const float* __restrict__ b_hh,        // (2048,)
    int t,
    float* __restrict__ h,                 // (64,512)
    float* __restrict__ c,                 // (64,512)
    float* __restrict__ hseq)              // (64,20,512)
{
    const int idx = blockIdx.x * TB + threadIdx.x;   // 0..32767
    const int b = idx >> 9;
    const int j = idx & 511;

    float g[4];
    #pragma unroll
    for (int comp = 0; comp < 4; ++comp) {
        const int col = comp * 512 + j;
        float v = b_hh[col] + eW[((size_t)b * 20 + t) * 2048 + col];
        #pragma unroll
        for (int s = 0; s < 8; ++s)
            v += gates_part[(size_t)s * 64 * 2048 + (size_t)b * 2048 + col];
        #pragma unroll
        for (int s = 0; s < 4; ++s)
            v += hga_part[(size_t)s * 64 * 4608 + (size_t)b * 4608 + 2560 + col];
        g[comp] = v;
    }
    const float si = 1.f / (1.f + expf(-g[0]));
    const float sf = 1.f / (1.f + expf(-g[1]));
    const float gg = tanhf(g[2]);
    const float so = 1.f / (1.f + expf(-g[3]));
    const float cn = sf * c[idx] + si * gg;
    c[idx] = cn;
    const float hn = so * tanhf(cn);
    h[idx] = hn;
    hseq[((size_t)b * 20 + t) * 512 + j] = hn;
}

// ------------------------- precompute helpers ------------------------------
__global__ __launch_bounds__(TB) void mean_feat(
    const float* __restrict__ features, float* __restrict__ mean_enc)
{
    const int b = blockIdx.y;
    const int e = blockIdx.x * TB + threadIdx.x;
    const float* f = features + (size_t)b * 196 * 2048 + e;
    float s = 0.f;
    #pragma unroll 4
    for (int p = 0; p < 196; ++p) s += f[(size_t)p * 2048];
    mean_enc[b * 2048 + e] = s * (1.f / 196.f);
}

__global__ __launch_bounds__(TB) void gather_emb(
    const int* __restrict__ captions,   // (64,21)
    const float* __restrict__ emb,      // (10000,512)
    float* __restrict__ embs)           // (64,20,512)
{
    const int bt = blockIdx.x;          // 0..1279
    const int b = bt / 20;
    const int t = bt % 20;
    const int tok = captions[b * 21 + t];
    for (int e = threadIdx.x; e < 512; e += TB)
        embs[(size_t)bt * 512 + e] = emb[(size_t)tok * 512 + e];
}

// h = sum_s h0p[s] + b_init_h ; c = sum_s c0p[s] + b_init_c
__global__ __launch_bounds__(TB) void reduce_hc(
    const float* __restrict__ h0p, const float* __restrict__ c0p,
    const float* __restrict__ bh0, const float* __restrict__ bc0,
    float* __restrict__ h, float* __restrict__ c)
{
    const int idx = blockIdx.x * TB + threadIdx.x;   // 0..65535
    const int half = idx >> 15;
    const int i = idx & 32767;
    const int j = i & 511;
    const float* P = half ? c0p : h0p;
    float v = half ? bc0[j] : bh0[j];
    #pragma unroll
    for (int s = 0; s < 8; ++s) v += P[(size_t)s * 64 * 512 + i];
    (half ? c : h)[i] = v;
}

// ---------------------------------------------------------------------------
extern "C" void kernel_launch(void* const* d_in, const int* in_sizes, int n_in,
                              void* d_out, int out_size, void* d_ws, size_t ws_size,
                              hipStream_t stream)
{
    const float* features  = (const float*)d_in[0];
    const int*   captions  = (const int*)  d_in[1];
    const float* W_enc_att = (const float*)d_in[2];
    const float* b_enc_att = (const float*)d_in[3];
    const float* W_dec_att = (const float*)d_in[4];
    const float* b_dec_att = (const float*)d_in[5];
    const float* W_full    = (const float*)d_in[6];
    // d_in[7] = b_full : uniform shift -> softmax invariant, unused
    const float* emb       = (const float*)d_in[8];
    const float* W_ih      = (const float*)d_in[9];
    const float* W_hh      = (const float*)d_in[10];
    const float* b_ih      = (const float*)d_in[11];
    const float* b_hh      = (const float*)d_in[12];
    const float* W_init_h  = (const float*)d_in[13];
    const float* b_init_h  = (const float*)d_in[14];
    const float* W_init_c  = (const float*)d_in[15];
    const float* b_init_c  = (const float*)d_in[16];
    const float* W_fbeta   = (const float*)d_in[17];
    const float* b_fbeta   = (const float*)d_in[18];
    const float* W_fc      = (const float*)d_in[19];
    const float* b_fc      = (const float*)d_in[20];
    float* out = (float*)d_out;

    float* ws = (float*)d_ws;
    size_t off = 0;
    auto alloc = [&](size_t n) { float* p = ws + off; off += n; return p; };

    float* att1   = alloc((size_t)12544 * 512);      // 25.7 MB
    float* eW     = alloc((size_t)64 * 20 * 2048);   // 10.5 MB
    float* embs   = alloc((size_t)64 * 20 * 512);    //  2.6 MB
    float* mean   = alloc(64 * 2048);
    float* hga    = alloc((size_t)4 * 64 * 4608);    //  4.7 MB
    float* gatesp = alloc((size_t)8 * 64 * 2048);    //  4.2 MB
    float* hseq   = alloc((size_t)64 * 20 * 512);    //  2.6 MB
    float* h      = alloc(64 * 512);
    float* c      = alloc(64 * 512);
    float* scores = alloc(64 * 196);
    float* gated  = alloc(64 * 2048);
    // one-time h0/c0 partials overlap the step buffers (used before loop only)
    float* h0p = hga;      // needs 8*64*512 = 256K floats <= 4*64*4608
    float* c0p = gatesp;   // needs 256K floats <= 8*64*2048

    // ---- precompute (step-invariant) ----
    mean_feat<<<dim3(8, 64), TB, 0, stream>>>(features, mean);
    gather_emb<<<1280, TB, 0, stream>>>(captions, emb, embs);
    // h0/c0 partials: (64 x 512), K=2048 split 8
    gemm_part<<<dim3(8, 8), TB, 0, stream>>>(mean, 2048, W_init_h, 512, h0p, 512, 512, 256);
    gemm_part<<<dim3(8, 8), TB, 0, stream>>>(mean, 2048, W_init_c, 512, c0p, 512, 512, 256);
    reduce_hc<<<256, TB, 0, stream>>>(h0p, c0p, b_init_h, b_init_c, h, c);
    // att1 = features @ W_enc_att + b : (12544 x 512), K=2048 ; M=98*128
    gemm128_k<<<dim3(8, 98), TB, 0, stream>>>(features, 2048, W_enc_att, 512,
                                              b_enc_att, att1, 512, 512, 2048);
    // eW = embs @ W_ih[:512,:] + b_ih : (1280 x 2048), K=512 ; M=10*128
    gemm128_k<<<dim3(32, 10), TB, 0, stream>>>(embs, 512, W_ih, 2048,
                                               b_ih, eW, 2048, 2048, 512);

    // ---- sequential decode (preds hoisted out) ----
    for (int t = 0; t < 20; ++t) {
        step_hgemm_part<<<dim3(72, 4), TB, 0, stream>>>(h, W_dec_att, W_fbeta, W_hh, hga);
        scores_k<<<dim3(64, 49), TB, 0, stream>>>(att1, hga, b_dec_att, W_full, scores);
        awe_gate<<<dim3(8, 64), TB, 0, stream>>>(scores, features, hga, b_fbeta, gated);
        // gates partials: gated(64x2048) @ W_ih[512: ,:], K=2048 split 8
        gemm_part<<<dim3(32, 8), TB, 0, stream>>>(gated, 2048,
                                                  W_ih + (size_t)512 * 2048, 2048,
                                                  gatesp, 2048, 2048, 256);
        lstm_pw<<<128, TB, 0, stream>>>(gatesp, hga, eW, b_hh, t, h, c, hseq);
    }

    // preds = hseq @ W_fc + b_fc : (1280 x 10000), K=512 ; rows = b*20+t
    gemm128_k<<<dim3(157, 10), TB, 0, stream>>>(hseq, 512, W_fc, 10000,
                                                b_fc, out, 10000, 10000, 512);
}

// Round 3
// 1321.725 us; speedup vs baseline: 4.5661x; 1.5587x over previous
//
#include <hip/hip_runtime.h>
#include <hip/hip_bf16.h>

// ---------------------------------------------------------------------------
// Shapes: B=64, P=196, ENC=2048, E=H=A=512, V=10000, L=21 -> T=20
// All GEMMs on MFMA via split-bf16 (hi+lo): C = Ah@Bh + Ah@Bl + Al@Bh.
// Packed fragment layout for a KxN (B-op) or MxK (A-op) matrix:
//   chunk(tile16 x kchunk32) -> 64 lanes x 8 bf16 (16B/lane), flat:
//   ((tile*KC + kc)*64 + ((k&31)>>3)*16 + (mn&15))*8 + (k&7)
// Weights packed once per replay; activations packed by producer kernels.
// ---------------------------------------------------------------------------

#define TB 256

typedef __bf16 bf16x8 __attribute__((ext_vector_type(8)));
typedef float f32x4 __attribute__((ext_vector_type(4)));
typedef unsigned short u16x8 __attribute__((ext_vector_type(8)));
typedef unsigned short u16x4 __attribute__((ext_vector_type(4)));
typedef unsigned short ushort_t;

__device__ __forceinline__ ushort_t f2bf(float x) {
    unsigned u = __builtin_bit_cast(unsigned, x);
    u += 0x7fffu + ((u >> 16) & 1u);          // round-to-nearest-even
    return (ushort_t)(u >> 16);
}
__device__ __forceinline__ float bf2f(ushort_t b) {
    return __builtin_bit_cast(float, (unsigned)b << 16);
}
// store one fp32 value into hi/lo packed arrays (A-operand layout, M rows x K cols)
__device__ __forceinline__ void store_pack(
    ushort_t* __restrict__ Ph, ushort_t* __restrict__ Pl,
    int KC, int m, int k, float v)
{
    const size_t flat = ((((size_t)(m >> 4) * KC + (k >> 5)) * 64)
                         + ((k & 31) >> 3) * 16 + (m & 15)) * 8 + (k & 7);
    const ushort_t h = f2bf(v);
    Ph[flat] = h;
    Pl[flat] = f2bf(v - bf2f(h));
}

// ------------------------- weight pack kernel ------------------------------
// one thread per (nt, kc, lane): reads 8 fp32 (coalesced across lanes), writes
// 16B hi + 16B lo. Zero-fills n >= Nsrc (for W_fc padding).
__global__ __launch_bounds__(TB) void pack_b(
    const float* __restrict__ W, int Nsrc, int ntCount, int KC,
    ushort_t* __restrict__ Bh, ushort_t* __restrict__ Bl, int ntBase)
{
    const int g = blockIdx.x * TB + threadIdx.x;
    const int lane = g & 63;
    const int kc = (g >> 6) % KC;
    const int nt = g / (64 * KC);
    if (nt >= ntCount) return;
    const int n = nt * 16 + (lane & 15);
    const int kb = kc * 32 + (lane >> 4) * 8;
    u16x8 hv, lv;
    #pragma unroll
    for (int e = 0; e < 8; ++e) {
        const float x = (n < Nsrc) ? W[(size_t)(kb + e) * Nsrc + n] : 0.f;
        const ushort_t h = f2bf(x);
        hv[e] = h;
        lv[e] = f2bf(x - bf2f(h));
    }
    const size_t flat = (((size_t)(ntBase + nt) * KC + kc) * 64 + lane) * 8;
    *(u16x8*)&Bh[flat] = hv;
    *(u16x8*)&Bl[flat] = lv;
}

// ------------------------- MFMA tile compute -------------------------------
template<int MT, int NT, int WR, int WC>
__device__ __forceinline__ void mfma_tile(
    const ushort_t* lds, int wr, int wc, int lane,
    f32x4 acc[MT / WR][NT / WC])
{
    constexpr int MFR = MT / WR, NFR = NT / WC;
    bf16x8 ah[MFR], al[MFR];
    #pragma unroll
    for (int i = 0; i < MFR; ++i) {
        ah[i] = __builtin_bit_cast(bf16x8, *(const u16x8*)&lds[(wr * MFR + i) * 512 + lane * 8]);
        al[i] = __builtin_bit_cast(bf16x8, *(const u16x8*)&lds[(MT + wr * MFR + i) * 512 + lane * 8]);
    }
    #pragma unroll
    for (int j = 0; j < NFR; ++j) {
        const bf16x8 bh = __builtin_bit_cast(bf16x8, *(const u16x8*)&lds[(2 * MT + wc * NFR + j) * 512 + lane * 8]);
        const bf16x8 bl = __builtin_bit_cast(bf16x8, *(const u16x8*)&lds[(2 * MT + NT + wc * NFR + j) * 512 + lane * 8]);
        #pragma unroll
        for (int i = 0; i < MFR; ++i) {
            acc[i][j] = __builtin_amdgcn_mfma_f32_16x16x32_bf16(ah[i], bh, acc[i][j], 0, 0, 0);
            acc[i][j] = __builtin_amdgcn_mfma_f32_16x16x32_bf16(ah[i], bl, acc[i][j], 0, 0, 0);
            acc[i][j] = __builtin_amdgcn_mfma_f32_16x16x32_bf16(al[i], bh, acc[i][j], 0, 0, 0);
        }
    }
}

// ------------------------- generic packed MFMA GEMM ------------------------
// grid: (nb, mb, ks). C += ks*cPartStride. K-chunks [ks*kcPer, +kcPer).
template<int MT, int NT, int WR, int WC>
__global__ __launch_bounds__(TB) void gemm_mfma(
    const ushort_t* __restrict__ Ah, const ushort_t* __restrict__ Al,
    const ushort_t* __restrict__ Bh, const ushort_t* __restrict__ Bl,
    int KC, int kcPer,
    const float* __restrict__ bias,
    float* __restrict__ C, int ldc, int Ncols, size_t cPartStride)
{
    constexpr int MFR = MT / WR, NFR = NT / WC, CH = 2 * (MT + NT);
    __shared__ __align__(16) ushort_t lds[CH * 512];
    const int tid = threadIdx.x, wid = tid >> 6, lane = tid & 63;
    const int wr = wid / WC, wc = wid % WC;
    const int nb = blockIdx.x, mb = blockIdx.y;
    const int kc0 = blockIdx.z * kcPer;

    f32x4 acc[MFR][NFR];
    #pragma unroll
    for (int i = 0; i < MFR; ++i)
        #pragma unroll
        for (int j = 0; j < NFR; ++j)
            acc[i][j] = f32x4{0.f, 0.f, 0.f, 0.f};

    for (int kc = kc0; kc < kc0 + kcPer; ++kc) {
        __syncthreads();
        #pragma unroll
        for (int cc = 0; cc < CH / 4; ++cc) {
            const int c = cc * 4 + wid;
            const ushort_t* src;
            if (c < MT)                src = Ah + ((size_t)(mb * MT + c) * KC + kc) * 512;
            else if (c < 2 * MT)       src = Al + ((size_t)(mb * MT + c - MT) * KC + kc) * 512;
            else if (c < 2 * MT + NT)  src = Bh + ((size_t)(nb * NT + c - 2 * MT) * KC + kc) * 512;
            else                       src = Bl + ((size_t)(nb * NT + c - 2 * MT - NT) * KC + kc) * 512;
            *(u16x8*)&lds[c * 512 + lane * 8] = *(const u16x8*)(src + lane * 8);
        }
        __syncthreads();
        mfma_tile<MT, NT, WR, WC>(lds, wr, wc, lane, acc);
    }

    C += (size_t)blockIdx.z * cPartStride;
    #pragma unroll
    for (int i = 0; i < MFR; ++i)
        #pragma unroll
        for (int j = 0; j < NFR; ++j) {
            const int col = nb * NT * 16 + (wc * NFR + j) * 16 + (lane & 15);
            if (col < Ncols) {
                const float bv = bias ? bias[col] : 0.f;
                const int rbase = mb * MT * 16 + (wr * MFR + i) * 16 + ((lane >> 4) << 2);
                #pragma unroll
                for (int r = 0; r < 4; ++r)
                    C[(size_t)(rbase + r) * ldc + col] = acc[i][j][r] + bv;
            }
        }
}

// ------------------------- att1 GEMM (A = fp32 features, converted on the fly)
// MT=8, NT=8, waves 2x2. A: M=12544 (mb over 98), K=2048 (KC=64), lda=2048.
__global__ __launch_bounds__(TB) void gemm_att1(
    const float* __restrict__ A,
    const ushort_t* __restrict__ Bh, const ushort_t* __restrict__ Bl,
    const float* __restrict__ bias, float* __restrict__ C)
{
    __shared__ __align__(16) ushort_t lds[32 * 512];
    const int tid = threadIdx.x, wid = tid >> 6, lane = tid & 63;
    const int wr = wid >> 1, wc = wid & 1;
    const int nb = blockIdx.x, mb = blockIdx.y;

    f32x4 acc[4][4];
    #pragma unroll
    for (int i = 0; i < 4; ++i)
        #pragma unroll
        for (int j = 0; j < 4; ++j)
            acc[i][j] = f32x4{0.f, 0.f, 0.f, 0.f};

    for (int kc = 0; kc < 64; ++kc) {
        __syncthreads();
        // B: 16 chunks (8 hi + 8 lo), 4 per wave
        #pragma unroll
        for (int cc = 0; cc < 4; ++cc) {
            const int c = cc * 4 + wid;
            const ushort_t* src = (c < 8)
                ? Bh + ((size_t)(nb * 8 + c) * 64 + kc) * 512
                : Bl + ((size_t)(nb * 8 + c - 8) * 64 + kc) * 512;
            *(u16x8*)&lds[(16 + c) * 512 + lane * 8] = *(const u16x8*)(src + lane * 8);
        }
        // A: 128 rows x 32 k fp32 -> hi/lo bf16 fragments
        #pragma unroll
        for (int p = 0; p < 4; ++p) {
            const int id = p * 256 + tid;
            const int row = id >> 3, c4 = id & 7;
            const float4 a = *(const float4*)&A[(size_t)(mb * 128 + row) * 2048 + kc * 32 + c4 * 4];
            const float xv[4] = {a.x, a.y, a.z, a.w};
            u16x4 hv, lv;
            #pragma unroll
            for (int q = 0; q < 4; ++q) {
                const ushort_t h = f2bf(xv[q]);
                hv[q] = h;
                lv[q] = f2bf(xv[q] - bf2f(h));
            }
            const int base = ((c4 >> 1) * 16 + (row & 15)) * 8 + (c4 & 1) * 4;
            const int chunk = row >> 4;
            *(u16x4*)&lds[chunk * 512 + base] = hv;
            *(u16x4*)&lds[(8 + chunk) * 512 + base] = lv;
        }
        __syncthreads();
        mfma_tile<8, 8, 2, 2>(lds, wr, wc, lane, acc);
    }

    #pragma unroll
    for (int i = 0; i < 4; ++i)
        #pragma unroll
        for (int j = 0; j < 4; ++j) {
            const int col = nb * 128 + (wc * 4 + j) * 16 + (lane & 15);
            const float bv = bias[col];
            const int rbase = mb * 128 + (wr * 4 + i) * 16 + ((lane >> 4) << 2);
            #pragma unroll
            for (int r = 0; r < 4; ++r)
                C[(size_t)(rbase + r) * 512 + col] = acc[i][j][r] + bv;
        }
}

// ------------------------- fp32 GEMM (one-time h0/c0 only) -----------------
__device__ __forceinline__ void gemm_body(
    float (*As)[68], float (*Ws)[68],
    const float* __restrict__ A, int lda,
    const float* __restrict__ W, int ldw,
    float* __restrict__ C, int ldc,
    int nTile, int N, int K)
{
    const int tid = threadIdx.x;
    const int tn = tid & 15;
    const int tm = tid >> 4;
    const int n0 = nTile * 64;

    float acc[4][4] = {{0.f}};

    for (int k0 = 0; k0 < K; k0 += 32) {
        {
            int r  = tid >> 3;
            int cc = (tid & 7) * 4;
            #pragma unroll
            for (int rr = 0; rr < 64; rr += 32) {
                const float4 a = *(const float4*)&A[(size_t)(rr + r) * lda + (k0 + cc)];
                As[cc + 0][rr + r] = a.x;
                As[cc + 1][rr + r] = a.y;
                As[cc + 2][rr + r] = a.z;
                As[cc + 3][rr + r] = a.w;
            }
        }
        {
            int r  = tid >> 4;
            int cc = (tid & 15) * 4;
            #pragma unroll
            for (int rr = 0; rr < 32; rr += 16) {
                const float4 w = *(const float4*)&W[(size_t)(k0 + rr + r) * ldw + (n0 + cc)];
                *(float4*)&Ws[rr + r][cc] = w;
            }
        }
        __syncthreads();
        #pragma unroll
        for (int kk = 0; kk < 32; ++kk) {
            const float4 a = *(const float4*)&As[kk][tm * 4];
            const float4 w = *(const float4*)&Ws[kk][tn * 4];
            const float av[4] = {a.x, a.y, a.z, a.w};
            const float wv[4] = {w.x, w.y, w.z, w.w};
            #pragma unroll
            for (int i = 0; i < 4; ++i)
                #pragma unroll
                for (int j = 0; j < 4; ++j)
                    acc[i][j] = fmaf(av[i], wv[j], acc[i][j]);
        }
        __syncthreads();
    }

    #pragma unroll
    for (int i = 0; i < 4; ++i) {
        const int m = tm * 4 + i;
        #pragma unroll
        for (int j = 0; j < 4; ++j)
            C[(size_t)m * ldc + (n0 + tn * 4 + j)] = acc[i][j];
    }
}

__global__ __launch_bounds__(TB) void gemm_part(
    const float* __restrict__ A, int lda,
    const float* __restrict__ W, int ldw,
    float* __restrict__ Cpart, int ldc, int N, int Kchunk)
{
    __shared__ float As[32][68];
    __shared__ float Ws[32][68];
    const int ks = blockIdx.y;
    gemm_body(As, Ws,
              A + (size_t)ks * Kchunk, lda,
              W + (size_t)ks * Kchunk * ldw, ldw,
              Cpart + (size_t)ks * 64 * ldc, ldc,
              blockIdx.x, N, Kchunk);
}

// ------------------------- attention scores --------------------------------
__global__ __launch_bounds__(TB) void scores_k(
    const float* __restrict__ att1,      // (64,196,512)
    const float* __restrict__ hga_part,  // (4,64,4608), att2 = cols 0..511
    const float* __restrict__ bd,        // (512,)
    const float* __restrict__ Wfull,     // (512,)
    float* __restrict__ scores)          // (64,196)
{
    const int b = blockIdx.x;
    const int tid = threadIdx.x;
    const int wave = tid >> 6;
    const int lane = tid & 63;

    __shared__ float a2[512];
    __shared__ float wf[512];

    for (int i = tid; i < 512; i += TB) {
        float v = bd[i];
        #pragma unroll
        for (int s = 0; s < 4; ++s)
            v += hga_part[(size_t)s * 64 * 4608 + (size_t)b * 4608 + i];
        a2[i] = v;
        wf[i] = Wfull[i];
    }
    __syncthreads();

    const int p = blockIdx.y * 4 + wave;
    const float* row = att1 + ((size_t)b * 196 + p) * 512;
    float s = 0.f;
    #pragma unroll
    for (int k = lane; k < 512; k += 64) {
        float v = row[k] + a2[k];
        s = fmaf(fmaxf(v, 0.f), wf[k], s);
    }
    #pragma unroll
    for (int o = 32; o; o >>= 1) s += __shfl_xor(s, o);
    if (lane == 0) scores[b * 196 + p] = s;
}

// ---------------- softmax (inline) + awe + gate -> gated_pack ---------------
__global__ __launch_bounds__(TB) void awe_gate(
    const float* __restrict__ scores,    // (64,196)
    const float* __restrict__ features,  // (64,196,2048)
    const float* __restrict__ hga_part,  // (4,64,4608), gpre = cols 512..2559
    const float* __restrict__ bf,        // (2048,)
    ushort_t* __restrict__ gPh, ushort_t* __restrict__ gPl)  // packed (64x2048, KC=64)
{
    const int b = blockIdx.y;
    const int tid = threadIdx.x;
    const int wave = tid >> 6;
    const int lane = tid & 63;
    const int eg = blockIdx.x * TB + tid;

    __shared__ float al[196];
    __shared__ float redm[4];
    __shared__ float reds[4];

    float sv = (tid < 196) ? scores[b * 196 + tid] : -1e30f;
    float m = sv;
    #pragma unroll
    for (int o = 32; o; o >>= 1) m = fmaxf(m, __shfl_xor(m, o));
    if (lane == 0) redm[wave] = m;
    __syncthreads();
    m = fmaxf(fmaxf(redm[0], redm[1]), fmaxf(redm[2], redm[3]));

    float e = (tid < 196) ? expf(sv - m) : 0.f;
    float s = e;
    #pragma unroll
    for (int o = 32; o; o >>= 1) s += __shfl_xor(s, o);
    if (lane == 0) reds[wave] = s;
    __syncthreads();
    s = reds[0] + reds[1] + reds[2] + reds[3];

    if (tid < 196) al[tid] = e / s;
    __syncthreads();

    const float* f = features + (size_t)b * 196 * 2048 + eg;
    float acc = 0.f;
    #pragma unroll 4
    for (int p = 0; p < 196; ++p) acc = fmaf(al[p], f[(size_t)p * 2048], acc);

    float gp = bf[eg];
    #pragma unroll
    for (int ss = 0; ss < 4; ++ss)
        gp += hga_part[(size_t)ss * 64 * 4608 + (size_t)b * 4608 + 512 + eg];
    const float gate = 1.f / (1.f + expf(-gp));
    store_pack(gPh, gPl, 64, b, eg, gate * acc);
}

// ------------------------- LSTM pointwise ----------------------------------
__global__ __launch_bounds__(TB) void lstm_pw(
    const float* __restrict__ gates_part,  // (8,64,2048)
    const float* __restrict__ hga_part,    // (4,64,4608), gh = cols 2560..4607
    const float* __restrict__ eW,          // (64,20,2048), includes b_ih
    const float* __restrict__ b_hh,        // (2048,)
    int t,
    float* __restrict__ c,                 // (64,512)
    ushort_t* __restrict__ hPh, ushort_t* __restrict__ hPl,   // packed h (64x512, KC=16)
    ushort_t* __restrict__ sPh, ushort_t* __restrict__ sPl)   // packed hseq (1280x512, KC=16)
{
    const int idx = blockIdx.x * TB + threadIdx.x;   // 0..32767
    const int b = idx >> 9;
    const int j = idx & 511;

    float g[4];
    #pragma unroll
    for (int comp = 0; comp < 4; ++comp) {
        const int col = comp * 512 + j;
        float v = b_hh[col] + eW[((size_t)b * 20 + t) * 2048 + col];
        #pragma unroll
        for (int s = 0; s < 8; ++s)
            v += gates_part[(size_t)s * 64 * 2048 + (size_t)b * 2048 + col];
        #pragma unroll
        for (int s = 0; s < 4; ++s)
            v += hga_part[(size_t)s * 64 * 4608 + (size_t)b * 4608 + 2560 + col];
        g[comp] = v;
    }
    const float si = 1.f / (1.f + expf(-g[0]));
    const float sf = 1.f / (1.f + expf(-g[1]));
    const float gg = tanhf(g[2]);
    const float so = 1.f / (1.f + expf(-g[3]));
    const float cn = sf * c[idx] + si * gg;
    c[idx] = cn;
    const float hn = so * tanhf(cn);
    store_pack(hPh, hPl, 16, b, j, hn);
    store_pack(sPh, sPl, 16, b * 20 + t, j, hn);
}

// ------------------------- precompute helpers ------------------------------
__global__ __launch_bounds__(TB) void mean_feat(
    const float* __restrict__ features, float* __restrict__ mean_enc)
{
    const int b = blockIdx.y;
    const int e = blockIdx.x * TB + threadIdx.x;
    const float* f = features + (size_t)b * 196 * 2048 + e;
    float s = 0.f;
    #pragma unroll 4
    for (int p = 0; p < 196; ++p) s += f[(size_t)p * 2048];
    mean_enc[b * 2048 + e] = s * (1.f / 196.f);
}

__global__ __launch_bounds__(TB) void gather_emb_pack(
    const int* __restrict__ captions,   // (64,21)
    const float* __restrict__ emb,      // (10000,512)
    ushort_t* __restrict__ Ph, ushort_t* __restrict__ Pl)  // packed embs (1280x512, KC=16)
{
    const int bt = blockIdx.x;          // 0..1279
    const int b = bt / 20;
    const int t = bt % 20;
    const int tok = captions[b * 21 + t];
    for (int e = threadIdx.x; e < 512; e += TB)
        store_pack(Ph, Pl, 16, bt, e, emb[(size_t)tok * 512 + e]);
}

// h0 -> packed h ; c0 -> fp32 c
__global__ __launch_bounds__(TB) void reduce_hc(
    const float* __restrict__ h0p, const float* __restrict__ c0p,
    const float* __restrict__ bh0, const float* __restrict__ bc0,
    ushort_t* __restrict__ hPh, ushort_t* __restrict__ hPl,
    float* __restrict__ c)
{
    const int idx = blockIdx.x * TB + threadIdx.x;   // 0..65535
    const int half = idx >> 15;
    const int i = idx & 32767;
    const int j = i & 511;
    const float* P = half ? c0p : h0p;
    float v = half ? bc0[j] : bh0[j];
    #pragma unroll
    for (int s = 0; s < 8; ++s) v += P[(size_t)s * 64 * 512 + i];
    if (half) c[i] = v;
    else      store_pack(hPh, hPl, 16, i >> 9, j, v);
}

// ---------------------------------------------------------------------------
extern "C" void kernel_launch(void* const* d_in, const int* in_sizes, int n_in,
                              void* d_out, int out_size, void* d_ws, size_t ws_size,
                              hipStream_t stream)
{
    const float* features  = (const float*)d_in[0];
    const int*   captions  = (const int*)  d_in[1];
    const float* W_enc_att = (const float*)d_in[2];
    const float* b_enc_att = (const float*)d_in[3];
    const float* W_dec_att = (const float*)d_in[4];
    const float* b_dec_att = (const float*)d_in[5];
    const float* W_full    = (const float*)d_in[6];
    // d_in[7] = b_full : uniform shift -> softmax invariant, unused
    const float* emb       = (const float*)d_in[8];
    const float* W_ih      = (const float*)d_in[9];
    const float* W_hh      = (const float*)d_in[10];
    const float* b_ih      = (const float*)d_in[11];
    const float* b_hh      = (const float*)d_in[12];
    const float* W_init_h  = (const float*)d_in[13];
    const float* b_init_h  = (const float*)d_in[14];
    const float* W_init_c  = (const float*)d_in[15];
    const float* b_init_c  = (const float*)d_in[16];
    const float* W_fbeta   = (const float*)d_in[17];
    const float* b_fbeta   = (const float*)d_in[18];
    const float* W_fc      = (const float*)d_in[19];
    const float* b_fc      = (const float*)d_in[20];
    float* out = (float*)d_out;
    (void)ws_size;

    float* ws = (float*)d_ws;
    size_t off = 0;
    auto alloc  = [&](size_t n) { float* p = ws + off; off += n; return p; };
    auto ualloc = [&](size_t n) { ushort_t* p = (ushort_t*)(ws + off); off += (n + 1) / 2; return p; };

    float* att1   = alloc((size_t)12544 * 512);
    float* eW     = alloc((size_t)64 * 20 * 2048);
    float* mean   = alloc(64 * 2048);
    float* hga    = alloc((size_t)4 * 64 * 4608);
    float* gatesp = alloc((size_t)8 * 64 * 2048);
    float* c      = alloc(64 * 512);
    float* scores = alloc(64 * 196);

    ushort_t* WencH = ualloc((size_t)32 * 64 * 512);   // W_enc_att  (K2048, N512)
    ushort_t* WencL = ualloc((size_t)32 * 64 * 512);
    ushort_t* WtopH = ualloc((size_t)128 * 16 * 512);  // W_ih[:512] (K512, N2048)
    ushort_t* WtopL = ualloc((size_t)128 * 16 * 512);
    ushort_t* Wih2H = ualloc((size_t)128 * 64 * 512);  // W_ih[512:] (K2048, N2048)
    ushort_t* Wih2L = ualloc((size_t)128 * 64 * 512);
    ushort_t* WdfhH = ualloc((size_t)288 * 16 * 512);  // [Wd|Wf|Wh] (K512, N4608)
    ushort_t* WdfhL = ualloc((size_t)288 * 16 * 512);
    ushort_t* WfcH  = ualloc((size_t)632 * 16 * 512);  // W_fc       (K512, N10000->10112)
    ushort_t* WfcL  = ualloc((size_t)632 * 16 * 512);
    ushort_t* embsH = ualloc((size_t)80 * 16 * 512);   // embs  (M1280, K512)
    ushort_t* embsL = ualloc((size_t)80 * 16 * 512);
    ushort_t* hPh   = ualloc((size_t)4 * 16 * 512);    // h     (M64, K512)
    ushort_t* hPl   = ualloc((size_t)4 * 16 * 512);
    ushort_t* gPh   = ualloc((size_t)4 * 64 * 512);    // gated (M64, K2048)
    ushort_t* gPl   = ualloc((size_t)4 * 64 * 512);
    ushort_t* sPh   = ualloc((size_t)80 * 16 * 512);   // hseq  (M1280, K512)
    ushort_t* sPl   = ualloc((size_t)80 * 16 * 512);

    // one-time h0/c0 partials reuse step buffers (consumed before loop)
    float* h0p = hga;      // 8*64*512 <= 4*64*4608
    float* c0p = gatesp;   // 8*64*512 <= 8*64*2048

    // ---- pack weights (per-replay, ~50 MB traffic) ----
    pack_b<<<512,  TB, 0, stream>>>(W_enc_att, 512, 32, 64, WencH, WencL, 0);
    pack_b<<<512,  TB, 0, stream>>>(W_ih, 2048, 128, 16, WtopH, WtopL, 0);
    pack_b<<<2048, TB, 0, stream>>>(W_ih + (size_t)512 * 2048, 2048, 128, 64, Wih2H, Wih2L, 0);
    pack_b<<<128,  TB, 0, stream>>>(W_dec_att, 512, 32, 16, WdfhH, WdfhL, 0);
    pack_b<<<512,  TB, 0, stream>>>(W_fbeta, 2048, 128, 16, WdfhH, WdfhL, 32);
    pack_b<<<512,  TB, 0, stream>>>(W_hh, 2048, 128, 16, WdfhH, WdfhL, 160);
    pack_b<<<2528, TB, 0, stream>>>(W_fc, 10000, 632, 16, WfcH, WfcL, 0);

    // ---- precompute (step-invariant) ----
    mean_feat<<<dim3(8, 64), TB, 0, stream>>>(features, mean);
    gather_emb_pack<<<1280, TB, 0, stream>>>(captions, emb, embsH, embsL);
    gemm_part<<<dim3(8, 8), TB, 0, stream>>>(mean, 2048, W_init_h, 512, h0p, 512, 512, 256);
    gemm_part<<<dim3(8, 8), TB, 0, stream>>>(mean, 2048, W_init_c, 512, c0p, 512, 512, 256);
    reduce_hc<<<256, TB, 0, stream>>>(h0p, c0p, b_init_h, b_init_c, hPh, hPl, c);
    // att1 = features @ W_enc_att + b : (12544 x 512), K=2048
    gemm_att1<<<dim3(4, 98), TB, 0, stream>>>(features, WencH, WencL, b_enc_att, att1);
    // eW = embs @ W_ih[:512] + b_ih : (1280 x 2048), K=512
    gemm_mfma<8, 8, 2, 2><<<dim3(16, 10, 1), TB, 0, stream>>>(
        embsH, embsL, WtopH, WtopL, 16, 16, b_ih, eW, 2048, 2048, 0);

    // ---- sequential decode ----
    for (int t = 0; t < 20; ++t) {
        // hga[ks] = h @ [Wd|Wf|Wh] partials : (64 x 4608), K=512 split 4
        gemm_mfma<4, 8, 2, 2><<<dim3(36, 1, 4), TB, 0, stream>>>(
            hPh, hPl, WdfhH, WdfhL, 16, 4, nullptr, hga, 4608, 4608, (size_t)64 * 4608);
        scores_k<<<dim3(64, 49), TB, 0, stream>>>(att1, hga, b_dec_att, W_full, scores);
        awe_gate<<<dim3(8, 64), TB, 0, stream>>>(scores, features, hga, b_fbeta, gPh, gPl);
        // gatesp[ks] = gated @ W_ih[512:] partials : (64 x 2048), K=2048 split 8
        gemm_mfma<4, 8, 2, 2><<<dim3(16, 1, 8), TB, 0, stream>>>(
            gPh, gPl, Wih2H, Wih2L, 64, 8, nullptr, gatesp, 2048, 2048, (size_t)64 * 2048);
        lstm_pw<<<128, TB, 0, stream>>>(gatesp, hga, eW, b_hh, t, c, hPh, hPl, sPh, sPl);
    }

    // preds = hseq @ W_fc + b_fc : (1280 x 10000), K=512
    gemm_mfma<8, 8, 2, 2><<<dim3(79, 10, 1), TB, 0, stream>>>(
        sPh, sPl, WfcH, WfcL, 16, 16, b_fc, out, 10000, 10000, 0);
}